// Round 9
// baseline (196.727 us; speedup 1.0000x reference)
//
#include <hip/hip_runtime.h>
#include <stdint.h>

#define B_ 4
#define N_ 2048
#define T_ 8
#define NL_ 64
#define DIM_ 1024
#define H_ 16
#define HD_ 64
#define TN_ (T_*NL_)   // 512

typedef __bf16 bf16x8 __attribute__((ext_vector_type(8)));
typedef float f32x4 __attribute__((ext_vector_type(4)));

__device__ __forceinline__ float b2f(unsigned short x) {
  union { uint32_t u; float f; } v; v.u = ((uint32_t)x) << 16; return v.f;
}
__device__ __forceinline__ unsigned short f2b(float f) {
  union { float f; uint32_t u; } v; v.f = f;
  uint32_t r = v.u + 0x7FFFu + ((v.u >> 16) & 1u);
  return (unsigned short)(r >> 16);
}

// direct HBM->LDS DMA, 16B per lane (global_load_lds_dwordx4), m104 contract.
__device__ __forceinline__ void gload_lds16(const unsigned short* g, unsigned short* l) {
  __builtin_amdgcn_global_load_lds(
      (const __attribute__((address_space(1))) uint32_t*)g,
      (__attribute__((address_space(3))) uint32_t*)l, 16, 0, 0);
}

// per-wave fp32-vs-bf16 storage detection (validated rounds 5-6).
__device__ __forceinline__ bool detect_isf(const unsigned short* text, int t) {
  int l = t & 63;
  int bad = 0;
  #pragma unroll
  for (int i = 0; i < 16; i++) {
    unsigned short w = text[l * 16 + i];
    int e = (w >> 7) & 0xFF;
    if (e != 0 && (e < 90 || e > 150)) bad++;
  }
  #pragma unroll
  for (int off = 32; off > 0; off >>= 1) bad += __shfl_xor(bad, off);
  return bad > 64;
}

// ---------------- fused preprocessing (4+2048+2049+4096 = 8197 blocks) ----------
#define PREP_TIMES 4
#define PREP_LN2   2048        // 4 rows/block, one per wave (no LDS, no barriers)
#define PREP_CAST  2049
#define PREP_TR    4096        // wq:1024, wkv:2048, wo:1024

__global__ __launch_bounds__(256) void prep_kernel(
    const void* __restrict__ locs, int* __restrict__ tt,
    const void* __restrict__ text, const void* __restrict__ lng,
    const void* __restrict__ lnb, unsigned short* __restrict__ tn,
    const void* __restrict__ media, unsigned short* __restrict__ mb,
    const void* __restrict__ bo, unsigned short* __restrict__ bob,
    const void* __restrict__ wq, unsigned short* __restrict__ wqt,
    const void* __restrict__ wkv, unsigned short* __restrict__ wkvt,
    const void* __restrict__ wo, unsigned short* __restrict__ wot,
    int* __restrict__ flag) {
  __shared__ __align__(16) unsigned char shraw[32 * 33 * 2];
  int gb = blockIdx.x;
  int t = threadIdx.x;
  bool isf = detect_isf((const unsigned short*)text, t);
  if (gb == 0 && t == 0) flag[0] = isf ? 1 : 0;   // for gemm_out (later dispatch)

  if (gb < PREP_TIMES) {                      // ---- times (block scan) ----
    int* red = (int*)shraw;
    int b = gb;
    const unsigned char* p8 = (const unsigned char*)locs;
    const int* p32 = (const int*)locs;
    int cnt = 0;
    for (int i = t; i < B_*N_; i += 256) cnt += (p8[i] != 0) ? 1 : 0;
    red[t] = cnt;
    __syncthreads();
    for (int off = 128; off > 0; off >>= 1) {
      if (t < off) red[t] += red[t + off];
      __syncthreads();
    }
    int total = red[0];
    __syncthreads();
    bool isb = (total >= 2 * T_);
    int x[8];
    int base = b * N_ + t * 8;
    if (isb) {
      #pragma unroll
      for (int i = 0; i < 8; i++) x[i] = (int)(p8[base + i] != 0);
    } else {
      #pragma unroll
      for (int i = 0; i < 8; i++) x[i] = (int)(p32[base + i] != 0);
    }
    #pragma unroll
    for (int i = 1; i < 8; i++) x[i] += x[i-1];
    int tot = x[7];
    red[t] = tot;
    __syncthreads();
    for (int off = 1; off < 256; off <<= 1) {
      int v = (t >= off) ? red[t - off] : 0;
      __syncthreads();
      red[t] += v;
      __syncthreads();
    }
    int excl = red[t] - tot;
    #pragma unroll
    for (int i = 0; i < 8; i++) tt[base + i] = excl + x[i];
    return;
  }
  gb -= PREP_TIMES;

  if (gb < PREP_LN2) {                        // ---- LayerNorm: wave per row ----
    int row = gb * 4 + (t >> 6);
    int l = t & 63;
    float f[16], gv_[16], cv_[16];
    if (isf) {
      const float4* x4 = (const float4*)text + (size_t)row * 256;
      const float4* g4 = (const float4*)lng;
      const float4* b4 = (const float4*)lnb;
      #pragma unroll
      for (int j = 0; j < 4; j++) {
        float4 xv = x4[l + 64*j];
        float4 gg = g4[l + 64*j];
        float4 bb = b4[l + 64*j];
        f[4*j+0]=xv.x; f[4*j+1]=xv.y; f[4*j+2]=xv.z; f[4*j+3]=xv.w;
        gv_[4*j+0]=gg.x; gv_[4*j+1]=gg.y; gv_[4*j+2]=gg.z; gv_[4*j+3]=gg.w;
        cv_[4*j+0]=bb.x; cv_[4*j+1]=bb.y; cv_[4*j+2]=bb.z; cv_[4*j+3]=bb.w;
      }
    } else {
      const ushort4* x4 = (const ushort4*)text + (size_t)row * 256;
      const ushort4* g4 = (const ushort4*)lng;
      const ushort4* b4 = (const ushort4*)lnb;
      #pragma unroll
      for (int j = 0; j < 4; j++) {
        ushort4 xv = x4[l + 64*j];
        ushort4 gg = g4[l + 64*j];
        ushort4 bb = b4[l + 64*j];
        f[4*j+0]=b2f(xv.x); f[4*j+1]=b2f(xv.y); f[4*j+2]=b2f(xv.z); f[4*j+3]=b2f(xv.w);
        gv_[4*j+0]=b2f(gg.x); gv_[4*j+1]=b2f(gg.y); gv_[4*j+2]=b2f(gg.z); gv_[4*j+3]=b2f(gg.w);
        cv_[4*j+0]=b2f(bb.x); cv_[4*j+1]=b2f(bb.y); cv_[4*j+2]=b2f(bb.z); cv_[4*j+3]=b2f(bb.w);
      }
    }
    float s = 0.f, s2 = 0.f;
    #pragma unroll
    for (int i = 0; i < 16; i++) { s += f[i]; s2 += f[i]*f[i]; }
    #pragma unroll
    for (int off = 32; off > 0; off >>= 1) { s += __shfl_xor(s, off); s2 += __shfl_xor(s2, off); }
    float mean = s * (1.0f / DIM_);
    float var  = s2 * (1.0f / DIM_) - mean * mean;
    float rs = rsqrtf(var + 1e-5f);
    ushort4* o4 = (ushort4*)(tn + (size_t)row * DIM_);
    #pragma unroll
    for (int j = 0; j < 4; j++) {
      ushort4 o;
      o.x = f2b((f[4*j+0] - mean) * rs * gv_[4*j+0] + cv_[4*j+0]);
      o.y = f2b((f[4*j+1] - mean) * rs * gv_[4*j+1] + cv_[4*j+1]);
      o.z = f2b((f[4*j+2] - mean) * rs * gv_[4*j+2] + cv_[4*j+2]);
      o.w = f2b((f[4*j+3] - mean) * rs * gv_[4*j+3] + cv_[4*j+3]);
      o4[l + 64*j] = o;
    }
    return;
  }
  gb -= PREP_LN2;

  if (gb < PREP_CAST) {                       // ---- media + bo cast ----
    const int N4M = (B_*T_*NL_*DIM_) / 4;     // 524288
    int i = gb * 256 + t;
    if (i < N4M) {
      ushort4 o;
      if (isf) {
        float4 v = ((const float4*)media)[i];
        o.x = f2b(v.x); o.y = f2b(v.y); o.z = f2b(v.z); o.w = f2b(v.w);
      } else {
        o = ((const ushort4*)media)[i];
      }
      ((ushort4*)mb)[i] = o;
    } else {
      int j = i - N4M;
      if (j < DIM_/4) {
        ushort4 o;
        if (isf) {
          float4 v = ((const float4*)bo)[j];
          o.x = f2b(v.x); o.y = f2b(v.y); o.z = f2b(v.z); o.w = f2b(v.w);
        } else {
          o = ((const ushort4*)bo)[j];
        }
        ((ushort4*)bob)[j] = o;
      }
    }
    return;
  }
  gb -= PREP_CAST;

  {                                           // ---- weight transpose+cast ----
    unsigned short (*tile)[33] = (unsigned short (*)[33])shraw;
    const void* src; unsigned short* dst; int C, zz, nx;
    if (gb < 1024)      { src = wq;  dst = wqt;  C = 1024; zz = gb;        nx = 32; }
    else if (gb < 3072) { src = wkv; dst = wkvt; C = 2048; zz = gb - 1024; nx = 64; }
    else                { src = wo;  dst = wot;  C = 1024; zz = gb - 3072; nx = 32; }
    const int R = 1024;
    int xi = zz % nx, yi = zz / nx;
    int bx = xi * 32, by = yi * 32;
    int x = t & 31, y = t >> 5;
    if (isf) {
      const float* s = (const float*)src;
      for (int i = y; i < 32; i += 8) tile[i][x] = f2b(s[(size_t)(by + i) * C + bx + x]);
    } else {
      const unsigned short* s = (const unsigned short*)src;
      for (int i = y; i < 32; i += 8) tile[i][x] = s[(size_t)(by + i) * C + bx + x];
    }
    __syncthreads();
    for (int i = y; i < 32; i += 8) dst[(size_t)(bx + i) * R + by + x] = tile[x][i];
  }
}

// ---------------- 128x128 MFMA GEMM core: ONE-barrier 3-buffer pipeline ------
// At iter i: read buf[i%3]; stage tile i+2 into buf[(i+2)%3] == buf[(i-1)%3]
// (its readers finished at iter i-1; the end-of-(i-1) barrier synced them).
// Single s_barrier per K-step (was 2). Counted vmcnt(4): after staging tile i+2,
// outstanding = {i+1:4, i+2:4} -> vmcnt(4) == tile i+1 landed; barrier makes
// that collective. Tails degrade 4 -> 0. T2 source-swizzle retained (free,
// and with 1 barrier the LDS-read path is closer to critical).
__device__ __forceinline__ void gemm128_core(const unsigned short* __restrict__ A,
                                             const unsigned short* __restrict__ Bt,
                                             unsigned short* __restrict__ C,
                                             float* __restrict__ Cf,
                                             const unsigned short* __restrict__ bias,
                                             int bid, int mtiles, int M, int N, int K,
                                             bool f32o, int t) {
  __shared__ unsigned short As[3][128][32];
  __shared__ unsigned short Bs[3][128][32];
  int m0 = (bid % mtiles) * 128, n0 = (bid / mtiles) * 128;
  int wave = t >> 6, lane = t & 63;
  int wr = wave >> 1, wc = wave & 1;
  f32x4 acc[4][4];
  #pragma unroll
  for (int i = 0; i < 4; i++)
    #pragma unroll
    for (int j = 0; j < 4; j++)
      #pragma unroll
      for (int r = 0; r < 4; r++) acc[i][j][r] = 0.f;
  int lr = lane & 15;
  int lk = (((lane >> 4) ^ ((lr >> 2) & 3)) & 3) * 8;        // swizzled read col
  int row0 = t >> 2,         kcp0 = (t & 3) * 8;             // physical LDS col
  int row1 = (t + 256) >> 2, kcp1 = ((t + 256) & 3) * 8;
  int kg0 = (((t & 3) ^ ((row0 >> 2) & 3)) & 3) * 8;         // pre-swizzled global col
  int kg1 = ((((t + 256) & 3) ^ ((row1 >> 2) & 3)) & 3) * 8;
  const unsigned short* a0 = A  + (size_t)(m0 + row0) * K + kg0;
  const unsigned short* a1 = A  + (size_t)(m0 + row1) * K + kg1;
  const unsigned short* b0 = Bt + (size_t)(n0 + row0) * K + kg0;
  const unsigned short* b1 = Bt + (size_t)(n0 + row1) * K + kg1;
#define STAGE_(buf, koff) do { \
    gload_lds16(a0 + (koff), &As[buf][row0][kcp0]); \
    gload_lds16(a1 + (koff), &As[buf][row1][kcp1]); \
    gload_lds16(b0 + (koff), &Bs[buf][row0][kcp0]); \
    gload_lds16(b1 + (koff), &Bs[buf][row1][kcp1]); \
  } while (0)
  // prologue: tiles 0,1 in flight; wait tile 0 (4 newest remain), collective
  STAGE_(0, 0);
  STAGE_(1, 32);
  asm volatile("s_waitcnt vmcnt(4)" ::: "memory");
  __builtin_amdgcn_s_barrier();
  int cur = 0;
  for (int k0 = 0; k0 < K; k0 += 32) {
    bf16x8 af[4], bfr[4];
    #pragma unroll
    for (int i = 0; i < 4; i++) af[i]  = *(const bf16x8*)(&As[cur][wr * 64 + i * 16 + lr][lk]);
    #pragma unroll
    for (int j = 0; j < 4; j++) bfr[j] = *(const bf16x8*)(&Bs[cur][wc * 64 + j * 16 + lr][lk]);
    asm volatile("s_waitcnt lgkmcnt(0)" ::: "memory");   // frags in regs
    __builtin_amdgcn_sched_barrier(0);                   // rule 18: pin
    if (k0 + 64 < K) {
      int nb2 = cur + 2; if (nb2 >= 3) nb2 -= 3;         // == buf[(i-1)%3], safe
      STAGE_(nb2, k0 + 64);
      __builtin_amdgcn_sched_barrier(0);
    }
    #pragma unroll
    for (int i = 0; i < 4; i++)
      #pragma unroll
      for (int j = 0; j < 4; j++)
        acc[i][j] = __builtin_amdgcn_mfma_f32_16x16x32_bf16(af[i], bfr[j], acc[i][j], 0, 0, 0);
    if (k0 + 64 < K) {
      asm volatile("s_waitcnt vmcnt(4)" ::: "memory");   // tile i+1 landed
    } else if (k0 + 32 < K) {
      asm volatile("s_waitcnt vmcnt(0)" ::: "memory");   // tail: last tile landed
    }
    __builtin_amdgcn_s_barrier();                        // the ONE barrier
    cur = (cur == 2) ? 0 : cur + 1;
  }
#undef STAGE_
  int rbase = (lane >> 4) * 4;
  int cbase = lane & 15;
  #pragma unroll
  for (int i = 0; i < 4; i++) {
    #pragma unroll
    for (int j = 0; j < 4; j++) {
      int row = m0 + wr * 64 + i * 16 + rbase;
      int col = n0 + wc * 64 + j * 16 + cbase;
      float bv = bias ? b2f(bias[col]) : 0.f;
      if (f32o) {
        #pragma unroll
        for (int r = 0; r < 4; r++)
          Cf[(size_t)(row + r) * N + col] = acc[i][j][r] + bv;
      } else {
        #pragma unroll
        for (int r = 0; r < 4; r++)
          C[(size_t)(row + r) * N + col] = f2b(acc[i][j][r] + bv);
      }
    }
  }
}

__global__ __launch_bounds__(256) void gemm_qkv(const unsigned short* __restrict__ tn,
                                                const unsigned short* __restrict__ wqt,
                                                unsigned short* __restrict__ qb,
                                                const unsigned short* __restrict__ mb,
                                                const unsigned short* __restrict__ wkvt,
                                                unsigned short* __restrict__ kvb) {
  int bid = blockIdx.x;
  if (bid < 512)
    gemm128_core(tn, wqt, qb, nullptr, nullptr, bid, 64, B_ * N_, DIM_, DIM_, false, threadIdx.x);
  else
    gemm128_core(mb, wkvt, kvb, nullptr, nullptr, bid - 512, 16, B_ * TN_, 2 * DIM_, DIM_, false, threadIdx.x);
}

__global__ __launch_bounds__(256) void gemm_out(const unsigned short* __restrict__ ao,
                                                const unsigned short* __restrict__ wot,
                                                unsigned short* __restrict__ C,
                                                float* __restrict__ Cf,
                                                const unsigned short* __restrict__ bias,
                                                const int* __restrict__ flag) {
  bool f32o = (*flag != 0);
  gemm128_core(ao, wot, C, Cf, bias, blockIdx.x, 64, B_ * N_, DIM_, DIM_, f32o, threadIdx.x);
}

// ---------------- MFMA attention: 1 wave per (b, 64-row tile, head) -------------
__global__ __launch_bounds__(64) void attn_mfma(const unsigned short* __restrict__ q,
                                                const unsigned short* __restrict__ kv,
                                                const int* __restrict__ tt,
                                                unsigned short* __restrict__ ao) {
  __shared__ unsigned short Vt[64][72];   // V^T [d][key]
  __shared__ unsigned short Ps[64][72];   // P [q][key]; reused as O staging
  int bid = blockIdx.x;
  int h  = bid & 15;
  int nt = (bid >> 4) & 31;
  int b  = bid >> 9;
  int bn0 = b * N_ + nt * 64;
  int lane = threadIdx.x & 63;
  int lr = lane & 15;
  int g  = lane >> 4;
  int g8 = g * 8;

  int tv = tt[bn0];             // tile-uniform by mask structure
  float vmul = (tv >= 1 && tv <= T_) ? 1.f : 0.f;
  int tvc = tv < 1 ? 1 : (tv > T_ ? T_ : tv);
  int kvrow0 = b * TN_ + (tvc - 1) * NL_;

  const unsigned short* vbase = kv + (size_t)kvrow0 * (2 * DIM_) + DIM_ + h * HD_;
  #pragma unroll
  for (int d0 = 0; d0 < 64; d0 += 8) {
    uint4 v = *(const uint4*)(vbase + (size_t)lane * (2 * DIM_) + d0);
    Vt[d0 + 0][lane] = (unsigned short)(v.x & 0xffff);
    Vt[d0 + 1][lane] = (unsigned short)(v.x >> 16);
    Vt[d0 + 2][lane] = (unsigned short)(v.y & 0xffff);
    Vt[d0 + 3][lane] = (unsigned short)(v.y >> 16);
    Vt[d0 + 4][lane] = (unsigned short)(v.z & 0xffff);
    Vt[d0 + 5][lane] = (unsigned short)(v.z >> 16);
    Vt[d0 + 6][lane] = (unsigned short)(v.w & 0xffff);
    Vt[d0 + 7][lane] = (unsigned short)(v.w >> 16);
  }

  f32x4 S[4][4];
  #pragma unroll
  for (int i = 0; i < 4; i++)
    #pragma unroll
    for (int j = 0; j < 4; j++)
      #pragma unroll
      for (int r = 0; r < 4; r++) S[i][j][r] = 0.f;
  #pragma unroll
  for (int ks = 0; ks < 2; ks++) {
    bf16x8 aQ[4], bK[4];
    #pragma unroll
    for (int mi = 0; mi < 4; mi++)
      aQ[mi] = *(const bf16x8*)(q + (size_t)(bn0 + mi * 16 + lr) * DIM_ + h * HD_ + ks * 32 + g8);
    #pragma unroll
    for (int ni = 0; ni < 4; ni++)
      bK[ni] = *(const bf16x8*)(kv + (size_t)(kvrow0 + ni * 16 + lr) * (2 * DIM_) + h * HD_ + ks * 32 + g8);
    #pragma unroll
    for (int mi = 0; mi < 4; mi++)
      #pragma unroll
      for (int ni = 0; ni < 4; ni++)
        S[mi][ni] = __builtin_amdgcn_mfma_f32_16x16x32_bf16(aQ[mi], bK[ni], S[mi][ni], 0, 0, 0);
  }

  #pragma unroll
  for (int mi = 0; mi < 4; mi++) {
    #pragma unroll
    for (int r = 0; r < 4; r++) {
      float mx = fmaxf(fmaxf(S[mi][0][r], S[mi][1][r]), fmaxf(S[mi][2][r], S[mi][3][r]));
      mx = fmaxf(mx, __shfl_xor(mx, 1));
      mx = fmaxf(mx, __shfl_xor(mx, 2));
      mx = fmaxf(mx, __shfl_xor(mx, 4));
      mx = fmaxf(mx, __shfl_xor(mx, 8));
      float e0 = __expf(S[mi][0][r] - mx);
      float e1 = __expf(S[mi][1][r] - mx);
      float e2 = __expf(S[mi][2][r] - mx);
      float e3 = __expf(S[mi][3][r] - mx);
      float sum = e0 + e1 + e2 + e3;
      sum += __shfl_xor(sum, 1);
      sum += __shfl_xor(sum, 2);
      sum += __shfl_xor(sum, 4);
      sum += __shfl_xor(sum, 8);
      float inv = 1.f / sum;
      int qrow = mi * 16 + g * 4 + r;
      Ps[qrow][ 0 + lr] = f2b(e0 * inv);
      Ps[qrow][16 + lr] = f2b(e1 * inv);
      Ps[qrow][32 + lr] = f2b(e2 * inv);
      Ps[qrow][48 + lr] = f2b(e3 * inv);
    }
  }
  __syncthreads();

  f32x4 O[4][4];
  #pragma unroll
  for (int i = 0; i < 4; i++)
    #pragma unroll
    for (int j = 0; j < 4; j++)
      #pragma unroll
      for (int r = 0; r < 4; r++) O[i][j][r] = 0.f;
  #pragma unroll
  for (int ks = 0; ks < 2; ks++) {
    bf16x8 aP[4], bV[4];
    #pragma unroll
    for (int mi = 0; mi < 4; mi++)
      aP[mi] = *(const bf16x8*)(&Ps[mi * 16 + lr][ks * 32 + g8]);
    #pragma unroll
    for (int ni = 0; ni < 4; ni++)
      bV[ni] = *(const bf16x8*)(&Vt[ni * 16 + lr][ks * 32 + g8]);
    #pragma unroll
    for (int mi = 0; mi < 4; mi++)
      #pragma unroll
      for (int ni = 0; ni < 4; ni++)
        O[mi][ni] = __builtin_amdgcn_mfma_f32_16x16x32_bf16(aP[mi], bV[ni], O[mi][ni], 0, 0, 0);
  }
  __syncthreads();

  #pragma unroll
  for (int mi = 0; mi < 4; mi++)
    #pragma unroll
    for (int ni = 0; ni < 4; ni++)
      #pragma unroll
      for (int r = 0; r < 4; r++)
        Ps[mi * 16 + g * 4 + r][ni * 16 + lr] = f2b(O[mi][ni][r] * vmul);
  __syncthreads();
  uint4* dst = (uint4*)(ao + (size_t)(bn0 + lane) * DIM_ + h * HD_);
  #pragma unroll
  for (int c = 0; c < 8; c++)
    dst[c] = *(const uint4*)(&Ps[lane][c * 8]);
}

extern "C" void kernel_launch(void* const* d_in, const int* in_sizes, int n_in,
                              void* d_out, int out_size, void* d_ws, size_t ws_size,
                              hipStream_t stream) {
  const void* text = d_in[0];
  const void* media = d_in[1];
  const void* mloc = d_in[2];
  const void* wq  = d_in[3];
  const void* wkv = d_in[4];
  const void* wo  = d_in[5];
  const void* bo  = d_in[6];
  const void* lng = d_in[7];
  const void* lnb = d_in[8];

  char* ws = (char*)d_ws;
  const size_t OFF_FLAG = (size_t)32 << 10;
  const size_t OFF_TN   = (size_t)64 << 10;
  const size_t OFF_WQT  = OFF_TN  + ((size_t)16 << 20) + ((size_t)64 << 10);
  const size_t OFF_WKVT = OFF_WQT + ((size_t)2 << 20);
  const size_t OFF_WOT  = OFF_WKVT + ((size_t)4 << 20);
  const size_t OFF_KV   = OFF_WOT + ((size_t)2 << 20);
  const size_t OFF_MB   = OFF_KV  + ((size_t)8 << 20);
  const size_t OFF_BO   = OFF_MB  + ((size_t)4 << 20);
  const size_t OFF_QB   = OFF_BO  + ((size_t)64 << 10);
  int* tt               = (int*)(ws + 0);
  int* flag             = (int*)(ws + OFF_FLAG);
  unsigned short* tn    = (unsigned short*)(ws + OFF_TN);
  unsigned short* ao    = tn;                               // reuse after q GEMM
  unsigned short* wqt   = (unsigned short*)(ws + OFF_WQT);
  unsigned short* wkvt  = (unsigned short*)(ws + OFF_WKVT);
  unsigned short* wot   = (unsigned short*)(ws + OFF_WOT);
  unsigned short* kvb   = (unsigned short*)(ws + OFF_KV);
  unsigned short* mb    = (unsigned short*)(ws + OFF_MB);
  unsigned short* bob   = (unsigned short*)(ws + OFF_BO);
  unsigned short* qb    = (unsigned short*)(ws + OFF_QB);

  // fused prep (flag + times + LN + cast + transposes): 4 launches total
  prep_kernel<<<PREP_TIMES + PREP_LN2 + PREP_CAST + PREP_TR, 256, 0, stream>>>(
      mloc, tt, text, lng, lnb, tn, media, mb, bo, bob,
      wq, wqt, wkv, wkvt, wo, wot, flag);

  gemm_qkv<<<768, 256, 0, stream>>>(tn, wqt, qb, mb, wkvt, kvb);
  attn_mfma<<<B_ * (N_/64) * H_, 64, 0, stream>>>(qb, kvb, tt, ao);
  gemm_out<<<512, 256, 0, stream>>>(ao, wot, (unsigned short*)d_out, (float*)d_out, bob, flag);
}

// Round 10
// 192.907 us; speedup vs baseline: 1.0198x; 1.0198x over previous
//
#include <hip/hip_runtime.h>
#include <stdint.h>

#define B_ 4
#define N_ 2048
#define T_ 8
#define NL_ 64
#define DIM_ 1024
#define H_ 16
#define HD_ 64
#define TN_ (T_*NL_)   // 512

typedef __bf16 bf16x8 __attribute__((ext_vector_type(8)));
typedef float f32x4 __attribute__((ext_vector_type(4)));

__device__ __forceinline__ float b2f(unsigned short x) {
  union { uint32_t u; float f; } v; v.u = ((uint32_t)x) << 16; return v.f;
}
__device__ __forceinline__ unsigned short f2b(float f) {
  union { float f; uint32_t u; } v; v.f = f;
  uint32_t r = v.u + 0x7FFFu + ((v.u >> 16) & 1u);
  return (unsigned short)(r >> 16);
}

// direct HBM->LDS DMA, 16B per lane (global_load_lds_dwordx4), m104 contract.
__device__ __forceinline__ void gload_lds16(const unsigned short* g, unsigned short* l) {
  __builtin_amdgcn_global_load_lds(
      (const __attribute__((address_space(1))) uint32_t*)g,
      (__attribute__((address_space(3))) uint32_t*)l, 16, 0, 0);
}

// per-wave fp32-vs-bf16 storage detection (validated rounds 5-9).
__device__ __forceinline__ bool detect_isf(const unsigned short* text, int t) {
  int l = t & 63;
  int bad = 0;
  #pragma unroll
  for (int i = 0; i < 16; i++) {
    unsigned short w = text[l * 16 + i];
    int e = (w >> 7) & 0xFF;
    if (e != 0 && (e < 90 || e > 150)) bad++;
  }
  #pragma unroll
  for (int off = 32; off > 0; off >>= 1) bad += __shfl_xor(bad, off);
  return bad > 64;
}

// ---------------- fused preprocessing (4+2048+2049+4096 = 8197 blocks) ----------
#define PREP_TIMES 4
#define PREP_LN2   2048        // 4 rows/block, one per wave (no LDS, no barriers)
#define PREP_CAST  2049
#define PREP_TR    4096        // wq:1024, wkv:2048, wo:1024

__global__ __launch_bounds__(256) void prep_kernel(
    const void* __restrict__ locs, int* __restrict__ tt,
    const void* __restrict__ text, const void* __restrict__ lng,
    const void* __restrict__ lnb, unsigned short* __restrict__ tn,
    const void* __restrict__ media, unsigned short* __restrict__ mb,
    const void* __restrict__ bo, unsigned short* __restrict__ bob,
    const void* __restrict__ wq, unsigned short* __restrict__ wqt,
    const void* __restrict__ wkv, unsigned short* __restrict__ wkvt,
    const void* __restrict__ wo, unsigned short* __restrict__ wot,
    int* __restrict__ flag) {
  __shared__ __align__(16) unsigned char shraw[32 * 33 * 2];
  int gb = blockIdx.x;
  int t = threadIdx.x;
  bool isf = detect_isf((const unsigned short*)text, t);
  if (gb == 0 && t == 0) flag[0] = isf ? 1 : 0;   // for gemm_out (later dispatch)

  if (gb < PREP_TIMES) {                      // ---- times (block scan) ----
    int* red = (int*)shraw;
    int b = gb;
    const unsigned char* p8 = (const unsigned char*)locs;
    const int* p32 = (const int*)locs;
    int cnt = 0;
    for (int i = t; i < B_*N_; i += 256) cnt += (p8[i] != 0) ? 1 : 0;
    red[t] = cnt;
    __syncthreads();
    for (int off = 128; off > 0; off >>= 1) {
      if (t < off) red[t] += red[t + off];
      __syncthreads();
    }
    int total = red[0];
    __syncthreads();
    bool isb = (total >= 2 * T_);
    int x[8];
    int base = b * N_ + t * 8;
    if (isb) {
      #pragma unroll
      for (int i = 0; i < 8; i++) x[i] = (int)(p8[base + i] != 0);
    } else {
      #pragma unroll
      for (int i = 0; i < 8; i++) x[i] = (int)(p32[base + i] != 0);
    }
    #pragma unroll
    for (int i = 1; i < 8; i++) x[i] += x[i-1];
    int tot = x[7];
    red[t] = tot;
    __syncthreads();
    for (int off = 1; off < 256; off <<= 1) {
      int v = (t >= off) ? red[t - off] : 0;
      __syncthreads();
      red[t] += v;
      __syncthreads();
    }
    int excl = red[t] - tot;
    #pragma unroll
    for (int i = 0; i < 8; i++) tt[base + i] = excl + x[i];
    return;
  }
  gb -= PREP_TIMES;

  if (gb < PREP_LN2) {                        // ---- LayerNorm: wave per row ----
    int row = gb * 4 + (t >> 6);
    int l = t & 63;
    float f[16], gv_[16], cv_[16];
    if (isf) {
      const float4* x4 = (const float4*)text + (size_t)row * 256;
      const float4* g4 = (const float4*)lng;
      const float4* b4 = (const float4*)lnb;
      #pragma unroll
      for (int j = 0; j < 4; j++) {
        float4 xv = x4[l + 64*j];
        float4 gg = g4[l + 64*j];
        float4 bb = b4[l + 64*j];
        f[4*j+0]=xv.x; f[4*j+1]=xv.y; f[4*j+2]=xv.z; f[4*j+3]=xv.w;
        gv_[4*j+0]=gg.x; gv_[4*j+1]=gg.y; gv_[4*j+2]=gg.z; gv_[4*j+3]=gg.w;
        cv_[4*j+0]=bb.x; cv_[4*j+1]=bb.y; cv_[4*j+2]=bb.z; cv_[4*j+3]=bb.w;
      }
    } else {
      const ushort4* x4 = (const ushort4*)text + (size_t)row * 256;
      const ushort4* g4 = (const ushort4*)lng;
      const ushort4* b4 = (const ushort4*)lnb;
      #pragma unroll
      for (int j = 0; j < 4; j++) {
        ushort4 xv = x4[l + 64*j];
        ushort4 gg = g4[l + 64*j];
        ushort4 bb = b4[l + 64*j];
        f[4*j+0]=b2f(xv.x); f[4*j+1]=b2f(xv.y); f[4*j+2]=b2f(xv.z); f[4*j+3]=b2f(xv.w);
        gv_[4*j+0]=b2f(gg.x); gv_[4*j+1]=b2f(gg.y); gv_[4*j+2]=b2f(gg.z); gv_[4*j+3]=b2f(gg.w);
        cv_[4*j+0]=b2f(bb.x); cv_[4*j+1]=b2f(bb.y); cv_[4*j+2]=b2f(bb.z); cv_[4*j+3]=b2f(bb.w);
      }
    }
    float s = 0.f, s2 = 0.f;
    #pragma unroll
    for (int i = 0; i < 16; i++) { s += f[i]; s2 += f[i]*f[i]; }
    #pragma unroll
    for (int off = 32; off > 0; off >>= 1) { s += __shfl_xor(s, off); s2 += __shfl_xor(s2, off); }
    float mean = s * (1.0f / DIM_);
    float var  = s2 * (1.0f / DIM_) - mean * mean;
    float rs = rsqrtf(var + 1e-5f);
    ushort4* o4 = (ushort4*)(tn + (size_t)row * DIM_);
    #pragma unroll
    for (int j = 0; j < 4; j++) {
      ushort4 o;
      o.x = f2b((f[4*j+0] - mean) * rs * gv_[4*j+0] + cv_[4*j+0]);
      o.y = f2b((f[4*j+1] - mean) * rs * gv_[4*j+1] + cv_[4*j+1]);
      o.z = f2b((f[4*j+2] - mean) * rs * gv_[4*j+2] + cv_[4*j+2]);
      o.w = f2b((f[4*j+3] - mean) * rs * gv_[4*j+3] + cv_[4*j+3]);
      o4[l + 64*j] = o;
    }
    return;
  }
  gb -= PREP_LN2;

  if (gb < PREP_CAST) {                       // ---- media + bo cast ----
    const int N4M = (B_*T_*NL_*DIM_) / 4;     // 524288
    int i = gb * 256 + t;
    if (i < N4M) {
      ushort4 o;
      if (isf) {
        float4 v = ((const float4*)media)[i];
        o.x = f2b(v.x); o.y = f2b(v.y); o.z = f2b(v.z); o.w = f2b(v.w);
      } else {
        o = ((const ushort4*)media)[i];
      }
      ((ushort4*)mb)[i] = o;
    } else {
      int j = i - N4M;
      if (j < DIM_/4) {
        ushort4 o;
        if (isf) {
          float4 v = ((const float4*)bo)[j];
          o.x = f2b(v.x); o.y = f2b(v.y); o.z = f2b(v.z); o.w = f2b(v.w);
        } else {
          o = ((const ushort4*)bo)[j];
        }
        ((ushort4*)bob)[j] = o;
      }
    }
    return;
  }
  gb -= PREP_CAST;

  {                                           // ---- weight transpose+cast ----
    unsigned short (*tile)[33] = (unsigned short (*)[33])shraw;
    const void* src; unsigned short* dst; int C, zz, nx;
    if (gb < 1024)      { src = wq;  dst = wqt;  C = 1024; zz = gb;        nx = 32; }
    else if (gb < 3072) { src = wkv; dst = wkvt; C = 2048; zz = gb - 1024; nx = 64; }
    else                { src = wo;  dst = wot;  C = 1024; zz = gb - 3072; nx = 32; }
    const int R = 1024;
    int xi = zz % nx, yi = zz / nx;
    int bx = xi * 32, by = yi * 32;
    int x = t & 31, y = t >> 5;
    if (isf) {
      const float* s = (const float*)src;
      for (int i = y; i < 32; i += 8) tile[i][x] = f2b(s[(size_t)(by + i) * C + bx + x]);
    } else {
      const unsigned short* s = (const unsigned short*)src;
      for (int i = y; i < 32; i += 8) tile[i][x] = s[(size_t)(by + i) * C + bx + x];
    }
    __syncthreads();
    for (int i = y; i < 32; i += 8) dst[(size_t)(bx + i) * R + by + x] = tile[x][i];
  }
}

// ---------------- 256x128 MFMA GEMM core: ONE-barrier 3-buffer pipeline --------
// 512 threads = 8 waves as 4(M) x 2(N); per-wave 64x64 output (acc[4][4]) —
// IDENTICAL per-wave pattern to the refcheck'd 128^2 core. Geometry change only:
// 2x tile rows -> 25% less staging per FLOP, 2 blocks/CU x 8 waves = 4 waves/SIMD,
// and qkv(384)/out(256) grids are single-shot resident (<=512 block capacity).
// Staging: 3 DMAs/thread (A chunks t, t+512; B chunk t). Row-XOR swizzle is
// congruent mod 4 across the three chunks -> shared kg column. vmcnt counts:
// 3/tile -> prologue vmcnt(3); steady vmcnt(3); tail vmcnt(0). Single barrier:
// stage tile i+2 into buf[(i-1)%3] whose readers were synced at barrier(i-1).
__device__ __forceinline__ void gemm256_core(const unsigned short* __restrict__ A,
                                             const unsigned short* __restrict__ Bt,
                                             unsigned short* __restrict__ C,
                                             float* __restrict__ Cf,
                                             const unsigned short* __restrict__ bias,
                                             int bid, int mtiles, int M, int N, int K,
                                             bool f32o, int t) {
  __shared__ unsigned short As[3][256][32];
  __shared__ unsigned short Bs[3][128][32];
  int m0 = (bid % mtiles) * 256, n0 = (bid / mtiles) * 128;
  int wave = t >> 6, lane = t & 63;
  int wr = wave >> 1, wc = wave & 1;          // 4 x 2 wave grid
  f32x4 acc[4][4];
  #pragma unroll
  for (int i = 0; i < 4; i++)
    #pragma unroll
    for (int j = 0; j < 4; j++)
      #pragma unroll
      for (int r = 0; r < 4; r++) acc[i][j][r] = 0.f;
  int lr = lane & 15;
  int lk = (((lane >> 4) ^ ((lr >> 2) & 3)) & 3) * 8;        // swizzled read col
  int rowA0 = t >> 2;                                        // 0..127
  int rowA1 = rowA0 + 128;                                   // 128..255
  int rowB  = rowA0;                                         // 0..127
  int kcp = (t & 3) * 8;                                     // physical LDS col
  int kg  = (((t & 3) ^ ((rowA0 >> 2) & 3)) & 3) * 8;        // pre-swizzled global col
  // (rowA1>>2)&3 == (rowA0>>2)&3 since 128>>2 = 32 ≡ 0 (mod 4) -> shared kg
  const unsigned short* aA0 = A  + (size_t)(m0 + rowA0) * K + kg;
  const unsigned short* aA1 = A  + (size_t)(m0 + rowA1) * K + kg;
  const unsigned short* bB  = Bt + (size_t)(n0 + rowB)  * K + kg;
#define STAGE_(buf, koff) do { \
    gload_lds16(aA0 + (koff), &As[buf][rowA0][kcp]); \
    gload_lds16(aA1 + (koff), &As[buf][rowA1][kcp]); \
    gload_lds16(bB  + (koff), &Bs[buf][rowB][kcp]); \
  } while (0)
  // prologue: tiles 0,1 in flight (6 DMAs/wave); wait tile 0 (3 newest remain)
  STAGE_(0, 0);
  STAGE_(1, 32);
  asm volatile("s_waitcnt vmcnt(3)" ::: "memory");
  __builtin_amdgcn_s_barrier();
  int cur = 0;
  for (int k0 = 0; k0 < K; k0 += 32) {
    bf16x8 af[4], bfr[4];
    #pragma unroll
    for (int i = 0; i < 4; i++) af[i]  = *(const bf16x8*)(&As[cur][wr * 64 + i * 16 + lr][lk]);
    #pragma unroll
    for (int j = 0; j < 4; j++) bfr[j] = *(const bf16x8*)(&Bs[cur][wc * 64 + j * 16 + lr][lk]);
    asm volatile("s_waitcnt lgkmcnt(0)" ::: "memory");   // frags in regs
    __builtin_amdgcn_sched_barrier(0);                   // rule 18: pin
    if (k0 + 64 < K) {
      int nb2 = cur + 2; if (nb2 >= 3) nb2 -= 3;         // == buf[(i-1)%3], safe
      STAGE_(nb2, k0 + 64);
      __builtin_amdgcn_sched_barrier(0);
    }
    #pragma unroll
    for (int i = 0; i < 4; i++)
      #pragma unroll
      for (int j = 0; j < 4; j++)
        acc[i][j] = __builtin_amdgcn_mfma_f32_16x16x32_bf16(af[i], bfr[j], acc[i][j], 0, 0, 0);
    if (k0 + 64 < K) {
      asm volatile("s_waitcnt vmcnt(3)" ::: "memory");   // tile i+1 landed
    } else if (k0 + 32 < K) {
      asm volatile("s_waitcnt vmcnt(0)" ::: "memory");   // tail: last tile landed
    }
    __builtin_amdgcn_s_barrier();                        // the ONE barrier
    cur = (cur == 2) ? 0 : cur + 1;
  }
#undef STAGE_
  int rbase = (lane >> 4) * 4;
  int cbase = lane & 15;
  #pragma unroll
  for (int i = 0; i < 4; i++) {
    #pragma unroll
    for (int j = 0; j < 4; j++) {
      int row = m0 + wr * 64 + i * 16 + rbase;
      int col = n0 + wc * 64 + j * 16 + cbase;
      float bv = bias ? b2f(bias[col]) : 0.f;
      if (f32o) {
        #pragma unroll
        for (int r = 0; r < 4; r++)
          Cf[(size_t)(row + r) * N + col] = acc[i][j][r] + bv;
      } else {
        #pragma unroll
        for (int r = 0; r < 4; r++)
          C[(size_t)(row + r) * N + col] = f2b(acc[i][j][r] + bv);
      }
    }
  }
}

// fused q-GEMM (blocks [0,256): 32 mtiles x 8 ntiles) +
//       kv-GEMM (blocks [256,384): 8 mtiles x 16 ntiles)
__global__ __launch_bounds__(512, 4) void gemm_qkv(const unsigned short* __restrict__ tn,
                                                   const unsigned short* __restrict__ wqt,
                                                   unsigned short* __restrict__ qb,
                                                   const unsigned short* __restrict__ mb,
                                                   const unsigned short* __restrict__ wkvt,
                                                   unsigned short* __restrict__ kvb) {
  int bid = blockIdx.x;
  if (bid < 256)
    gemm256_core(tn, wqt, qb, nullptr, nullptr, bid, 32, B_ * N_, DIM_, DIM_, false, threadIdx.x);
  else
    gemm256_core(mb, wkvt, kvb, nullptr, nullptr, bid - 256, 8, B_ * TN_, 2 * DIM_, DIM_, false, threadIdx.x);
}

__global__ __launch_bounds__(512, 4) void gemm_out(const unsigned short* __restrict__ ao,
                                                   const unsigned short* __restrict__ wot,
                                                   unsigned short* __restrict__ C,
                                                   float* __restrict__ Cf,
                                                   const unsigned short* __restrict__ bias,
                                                   const int* __restrict__ flag) {
  bool f32o = (*flag != 0);
  gemm256_core(ao, wot, C, Cf, bias, blockIdx.x, 32, B_ * N_, DIM_, DIM_, f32o, threadIdx.x);
}

// ---------------- MFMA attention: 1 wave per (b, 64-row tile, head) -------------
__global__ __launch_bounds__(64) void attn_mfma(const unsigned short* __restrict__ q,
                                                const unsigned short* __restrict__ kv,
                                                const int* __restrict__ tt,
                                                unsigned short* __restrict__ ao) {
  __shared__ unsigned short Vt[64][72];   // V^T [d][key]
  __shared__ unsigned short Ps[64][72];   // P [q][key]; reused as O staging
  int bid = blockIdx.x;
  int h  = bid & 15;
  int nt = (bid >> 4) & 31;
  int b  = bid >> 9;
  int bn0 = b * N_ + nt * 64;
  int lane = threadIdx.x & 63;
  int lr = lane & 15;
  int g  = lane >> 4;
  int g8 = g * 8;

  int tv = tt[bn0];             // tile-uniform by mask structure
  float vmul = (tv >= 1 && tv <= T_) ? 1.f : 0.f;
  int tvc = tv < 1 ? 1 : (tv > T_ ? T_ : tv);
  int kvrow0 = b * TN_ + (tvc - 1) * NL_;

  const unsigned short* vbase = kv + (size_t)kvrow0 * (2 * DIM_) + DIM_ + h * HD_;
  #pragma unroll
  for (int d0 = 0; d0 < 64; d0 += 8) {
    uint4 v = *(const uint4*)(vbase + (size_t)lane * (2 * DIM_) + d0);
    Vt[d0 + 0][lane] = (unsigned short)(v.x & 0xffff);
    Vt[d0 + 1][lane] = (unsigned short)(v.x >> 16);
    Vt[d0 + 2][lane] = (unsigned short)(v.y & 0xffff);
    Vt[d0 + 3][lane] = (unsigned short)(v.y >> 16);
    Vt[d0 + 4][lane] = (unsigned short)(v.z & 0xffff);
    Vt[d0 + 5][lane] = (unsigned short)(v.z >> 16);
    Vt[d0 + 6][lane] = (unsigned short)(v.w & 0xffff);
    Vt[d0 + 7][lane] = (unsigned short)(v.w >> 16);
  }

  f32x4 S[4][4];
  #pragma unroll
  for (int i = 0; i < 4; i++)
    #pragma unroll
    for (int j = 0; j < 4; j++)
      #pragma unroll
      for (int r = 0; r < 4; r++) S[i][j][r] = 0.f;
  #pragma unroll
  for (int ks = 0; ks < 2; ks++) {
    bf16x8 aQ[4], bK[4];
    #pragma unroll
    for (int mi = 0; mi < 4; mi++)
      aQ[mi] = *(const bf16x8*)(q + (size_t)(bn0 + mi * 16 + lr) * DIM_ + h * HD_ + ks * 32 + g8);
    #pragma unroll
    for (int ni = 0; ni < 4; ni++)
      bK[ni] = *(const bf16x8*)(kv + (size_t)(kvrow0 + ni * 16 + lr) * (2 * DIM_) + h * HD_ + ks * 32 + g8);
    #pragma unroll
    for (int mi = 0; mi < 4; mi++)
      #pragma unroll
      for (int ni = 0; ni < 4; ni++)
        S[mi][ni] = __builtin_amdgcn_mfma_f32_16x16x32_bf16(aQ[mi], bK[ni], S[mi][ni], 0, 0, 0);
  }

  #pragma unroll
  for (int mi = 0; mi < 4; mi++) {
    #pragma unroll
    for (int r = 0; r < 4; r++) {
      float mx = fmaxf(fmaxf(S[mi][0][r], S[mi][1][r]), fmaxf(S[mi][2][r], S[mi][3][r]));
      mx = fmaxf(mx, __shfl_xor(mx, 1));
      mx = fmaxf(mx, __shfl_xor(mx, 2));
      mx = fmaxf(mx, __shfl_xor(mx, 4));
      mx = fmaxf(mx, __shfl_xor(mx, 8));
      float e0 = __expf(S[mi][0][r] - mx);
      float e1 = __expf(S[mi][1][r] - mx);
      float e2 = __expf(S[mi][2][r] - mx);
      float e3 = __expf(S[mi][3][r] - mx);
      float sum = e0 + e1 + e2 + e3;
      sum += __shfl_xor(sum, 1);
      sum += __shfl_xor(sum, 2);
      sum += __shfl_xor(sum, 4);
      sum += __shfl_xor(sum, 8);
      float inv = 1.f / sum;
      int qrow = mi * 16 + g * 4 + r;
      Ps[qrow][ 0 + lr] = f2b(e0 * inv);
      Ps[qrow][16 + lr] = f2b(e1 * inv);
      Ps[qrow][32 + lr] = f2b(e2 * inv);
      Ps[qrow][48 + lr] = f2b(e3 * inv);
    }
  }
  __syncthreads();

  f32x4 O[4][4];
  #pragma unroll
  for (int i = 0; i < 4; i++)
    #pragma unroll
    for (int j = 0; j < 4; j++)
      #pragma unroll
      for (int r = 0; r < 4; r++) O[i][j][r] = 0.f;
  #pragma unroll
  for (int ks = 0; ks < 2; ks++) {
    bf16x8 aP[4], bV[4];
    #pragma unroll
    for (int mi = 0; mi < 4; mi++)
      aP[mi] = *(const bf16x8*)(&Ps[mi * 16 + lr][ks * 32 + g8]);
    #pragma unroll
    for (int ni = 0; ni < 4; ni++)
      bV[ni] = *(const bf16x8*)(&Vt[ni * 16 + lr][ks * 32 + g8]);
    #pragma unroll
    for (int mi = 0; mi < 4; mi++)
      #pragma unroll
      for (int ni = 0; ni < 4; ni++)
        O[mi][ni] = __builtin_amdgcn_mfma_f32_16x16x32_bf16(aP[mi], bV[ni], O[mi][ni], 0, 0, 0);
  }
  __syncthreads();

  #pragma unroll
  for (int mi = 0; mi < 4; mi++)
    #pragma unroll
    for (int ni = 0; ni < 4; ni++)
      #pragma unroll
      for (int r = 0; r < 4; r++)
        Ps[mi * 16 + g * 4 + r][ni * 16 + lr] = f2b(O[mi][ni][r] * vmul);
  __syncthreads();
  uint4* dst = (uint4*)(ao + (size_t)(bn0 + lane) * DIM_ + h * HD_);
  #pragma unroll
  for (int c = 0; c < 8; c++)
    dst[c] = *(const uint4*)(&Ps[lane][c * 8]);
}

extern "C" void kernel_launch(void* const* d_in, const int* in_sizes, int n_in,
                              void* d_out, int out_size, void* d_ws, size_t ws_size,
                              hipStream_t stream) {
  const void* text = d_in[0];
  const void* media = d_in[1];
  const void* mloc = d_in[2];
  const void* wq  = d_in[3];
  const void* wkv = d_in[4];
  const void* wo  = d_in[5];
  const void* bo  = d_in[6];
  const void* lng = d_in[7];
  const void* lnb = d_in[8];

  char* ws = (char*)d_ws;
  const size_t OFF_FLAG = (size_t)32 << 10;
  const size_t OFF_TN   = (size_t)64 << 10;
  const size_t OFF_WQT  = OFF_TN  + ((size_t)16 << 20) + ((size_t)64 << 10);
  const size_t OFF_WKVT = OFF_WQT + ((size_t)2 << 20);
  const size_t OFF_WOT  = OFF_WKVT + ((size_t)4 << 20);
  const size_t OFF_KV   = OFF_WOT + ((size_t)2 << 20);
  const size_t OFF_MB   = OFF_KV  + ((size_t)8 << 20);
  const size_t OFF_BO   = OFF_MB  + ((size_t)4 << 20);
  const size_t OFF_QB   = OFF_BO  + ((size_t)64 << 10);
  int* tt               = (int*)(ws + 0);
  int* flag             = (int*)(ws + OFF_FLAG);
  unsigned short* tn    = (unsigned short*)(ws + OFF_TN);
  unsigned short* ao    = tn;                               // reuse after q GEMM
  unsigned short* wqt   = (unsigned short*)(ws + OFF_WQT);
  unsigned short* wkvt  = (unsigned short*)(ws + OFF_WKVT);
  unsigned short* wot   = (unsigned short*)(ws + OFF_WOT);
  unsigned short* kvb   = (unsigned short*)(ws + OFF_KV);
  unsigned short* mb    = (unsigned short*)(ws + OFF_MB);
  unsigned short* bob   = (unsigned short*)(ws + OFF_BO);
  unsigned short* qb    = (unsigned short*)(ws + OFF_QB);

  // fused prep (flag + times + LN + cast + transposes): 4 launches total
  prep_kernel<<<PREP_TIMES + PREP_LN2 + PREP_CAST + PREP_TR, 256, 0, stream>>>(
      mloc, tt, text, lng, lnb, tn, media, mb, bo, bob,
      wq, wqt, wkv, wkvt, wo, wot, flag);

  // fused q (256 blocks) + kv (128 blocks) 256x128-tile GEMM — single-shot grid
  gemm_qkv<<<384, 512, 0, stream>>>(tn, wqt, qb, mb, wkvt, kvb);
  attn_mfma<<<B_ * (N_/64) * H_, 64, 0, stream>>>(qb, kvb, tt, ao);
  gemm_out<<<256, 512, 0, stream>>>(ao, wot, (unsigned short*)d_out, (float*)d_out, bob, flag);
}